// Round 3
// baseline (783.204 us; speedup 1.0000x reference)
//
#include <hip/hip_runtime.h>

// ScaledDotProductAttention, MI355X. fp32 in/out.
// attn [2,16,2048,2048] fp32 (512 MiB) + out [2,16,2048,64] fp32, concat in d_out.
// K1: rowsum with split-bf16 (hi/lo) QK^T (consistent with K2), writes 1/rowsum
//     into the out-slice head for its (bh,qt) tile.
// K2: split-bf16 QK^T recompute -> exp2 -> *rinv -> attn store (nontemporal)
//     + fp16 P stash -> fp16 MFMA PV -> out store (overwrites the rinv slot last).

#define S_LEN 2048
#define D_HEAD 64
#define QB 64
#define KB 128
#define NCHUNK (S_LEN / KB)     // 16
#define KPAD 72                  // 64 + 8 (bf16) -> 144B row stride = 9*16B (odd) -> conflict-free
#define PPAD 136                 // 128 + 8 (fp16) -> 272B row stride = 17*16B (odd)
#define ATTN_ELEMS 134217728ull  // 2*16*2048*2048
#define LOG2E 1.44269504088896340736f

typedef short short8 __attribute__((ext_vector_type(8)));
typedef _Float16 half8 __attribute__((ext_vector_type(8)));
typedef float f32x16 __attribute__((ext_vector_type(16)));
typedef float floatx4 __attribute__((ext_vector_type(4)));
typedef unsigned short ushort8v __attribute__((ext_vector_type(8)));

#if __has_builtin(__builtin_amdgcn_exp2f)
#define EXP2F(x) __builtin_amdgcn_exp2f(x)
#else
#define EXP2F(x) exp2f(x)
#endif

static __device__ __forceinline__ unsigned short f2bf(float f) {
  unsigned u = __builtin_bit_cast(unsigned, f);
  u += 0x7fffu + ((u >> 16) & 1u);   // RTNE
  return (unsigned short)(u >> 16);
}
static __device__ __forceinline__ float bf2f(unsigned short h) {
  unsigned u = ((unsigned)h) << 16;
  return __builtin_bit_cast(float, u);
}
static __device__ __forceinline__ unsigned short f2h(float f) {
  return __builtin_bit_cast(unsigned short, (_Float16)f);
}

// ---------------- Kernel 1: row-sum of exp(scores), split-bf16 ----------------
__global__ __launch_bounds__(512, 4) void k_rowsum(
    const float* __restrict__ q, const float* __restrict__ k,
    float* __restrict__ outbuf) {
  __shared__ __align__(16) unsigned short KhiS[KB * KPAD];
  __shared__ __align__(16) unsigned short KloS[KB * KPAD];
  __shared__ float rsum_s[QB];

  const int tid = threadIdx.x;
  const int lane = tid & 63;
  const int wid = tid >> 6;
  const int rg = wid & 1, cg = wid >> 1;  // 2 row-groups x 4 col-groups
  const int bh = blockIdx.x >> 5;
  const int qt = blockIdx.x & 31;

  const float* Q = q + (size_t)bh * S_LEN * D_HEAD;
  const float* K = k + (size_t)bh * S_LEN * D_HEAD;
  float* rinv_out = outbuf + ATTN_ELEMS + (size_t)bh * S_LEN * D_HEAD +
                    (size_t)qt * QB * D_HEAD;

  if (tid < QB) rsum_s[tid] = 0.0f;

  // Q A-frags, hi/lo split, pre-scaled by 1/8.
  // A layout (32x32x16): row = lane&31, k = (lane>>5)*8 + j
  const int arow = qt * QB + rg * 32 + (lane & 31);
  const float* qp = Q + (size_t)arow * D_HEAD + ((lane >> 5) * 8);
  short8 ahi[4], alo[4];
#pragma unroll
  for (int ks = 0; ks < 4; ++ks) {
    floatx4 x0 = *(const floatx4*)(qp + ks * 16);
    floatx4 x1 = *(const floatx4*)(qp + ks * 16 + 4);
    ushort8v uh, ul;
#pragma unroll
    for (int j = 0; j < 4; ++j) {
      float xa = x0[j] * 0.125f;
      unsigned short ha = f2bf(xa);
      uh[j] = ha; ul[j] = f2bf(xa - bf2f(ha));
      float xb = x1[j] * 0.125f;
      unsigned short hb = f2bf(xb);
      uh[4 + j] = hb; ul[4 + j] = f2bf(xb - bf2f(hb));
    }
    ahi[ks] = __builtin_bit_cast(short8, uh);
    alo[ks] = __builtin_bit_cast(short8, ul);
  }

  float psum[16];
#pragma unroll
  for (int i = 0; i < 16; ++i) psum[i] = 0.0f;

  const int srow = tid >> 2;
  const int scol = (tid & 3) * 16;
  const int bcol = cg * 32 + (lane & 31);
  const int boff = (lane >> 5) * 8;

  for (int ch = 0; ch < NCHUNK; ++ch) {
    const int kk0 = ch * KB;
    {  // stage K hi/lo (bf16) into padded LDS
      const float* src = K + (size_t)(kk0 + srow) * D_HEAD + scol;
      floatx4 v0 = *(const floatx4*)(src);
      floatx4 v1 = *(const floatx4*)(src + 4);
      floatx4 v2 = *(const floatx4*)(src + 8);
      floatx4 v3 = *(const floatx4*)(src + 12);
      ushort8v h0, h1, l0, l1;
#pragma unroll
      for (int j = 0; j < 4; ++j) {
        unsigned short a0 = f2bf(v0[j]); h0[j] = a0; l0[j] = f2bf(v0[j] - bf2f(a0));
        unsigned short a1 = f2bf(v1[j]); h0[4+j] = a1; l0[4+j] = f2bf(v1[j] - bf2f(a1));
        unsigned short a2 = f2bf(v2[j]); h1[j] = a2; l1[j] = f2bf(v2[j] - bf2f(a2));
        unsigned short a3 = f2bf(v3[j]); h1[4+j] = a3; l1[4+j] = f2bf(v3[j] - bf2f(a3));
      }
      *(ushort8v*)&KhiS[srow * KPAD + scol] = h0;
      *(ushort8v*)&KhiS[srow * KPAD + scol + 8] = h1;
      *(ushort8v*)&KloS[srow * KPAD + scol] = l0;
      *(ushort8v*)&KloS[srow * KPAD + scol + 8] = l1;
    }
    __syncthreads();
    f32x16 acc = {};
#pragma unroll
    for (int ks = 0; ks < 4; ++ks) {
      ushort8v bhu = *(const ushort8v*)&KhiS[bcol * KPAD + ks * 16 + boff];
      ushort8v blu = *(const ushort8v*)&KloS[bcol * KPAD + ks * 16 + boff];
      short8 bh8 = __builtin_bit_cast(short8, bhu);
      short8 bl8 = __builtin_bit_cast(short8, blu);
      acc = __builtin_amdgcn_mfma_f32_32x32x16_bf16(alo[ks], bh8, acc, 0, 0, 0);
      acc = __builtin_amdgcn_mfma_f32_32x32x16_bf16(ahi[ks], bl8, acc, 0, 0, 0);
      acc = __builtin_amdgcn_mfma_f32_32x32x16_bf16(ahi[ks], bh8, acc, 0, 0, 0);
    }
#pragma unroll
    for (int i = 0; i < 16; ++i) psum[i] += EXP2F(acc[i] * LOG2E);
    __syncthreads();
  }

  // reduce over the 32 columns held by lanes (lane&31); xor<=16 stays in-half,
  // which matches the (lane>>5)-dependent row base.
#pragma unroll
  for (int off = 1; off < 32; off <<= 1) {
#pragma unroll
    for (int i = 0; i < 16; ++i) psum[i] += __shfl_xor(psum[i], off, 64);
  }
  if ((lane & 31) == 0) {
    const int rbase = rg * 32 + 4 * (lane >> 5);
#pragma unroll
    for (int i = 0; i < 16; ++i)
      atomicAdd(&rsum_s[rbase + (i & 3) + 8 * (i >> 2)], psum[i]);
  }
  __syncthreads();
  if (tid < QB) rinv_out[tid] = 1.0f / rsum_s[tid];
}

// ---------------- Kernel 2: attn + out ----------------
__global__ __launch_bounds__(512, 4) void k_attn(
    const float* __restrict__ q, const float* __restrict__ k,
    const float* __restrict__ v, float* __restrict__ outbuf) {
  __shared__ __align__(16) unsigned short KhiS[KB * KPAD];
  __shared__ __align__(16) unsigned short KloS[KB * KPAD];
  __shared__ __align__(16) unsigned short Pst[QB * PPAD];
  __shared__ __align__(16) unsigned short VtS[D_HEAD * PPAD];
  __shared__ float rinv_s[QB];

  const int tid = threadIdx.x;
  const int lane = tid & 63;
  const int wid = tid >> 6;
  const int rg = wid & 1, cg = wid >> 1;                 // QK roles
  const int dg = (wid >> 1) & 1, kh = wid >> 2;          // PV roles (rg reused)
  const int bh = blockIdx.x >> 5;
  const int qt = blockIdx.x & 31;

  const float* Q = q + (size_t)bh * S_LEN * D_HEAD;
  const float* K = k + (size_t)bh * S_LEN * D_HEAD;
  const float* V = v + (size_t)bh * S_LEN * D_HEAD;
  float* attn_base = outbuf + (size_t)bh * S_LEN * S_LEN + (size_t)qt * QB * S_LEN;
  float* out_base = outbuf + ATTN_ELEMS + (size_t)bh * S_LEN * D_HEAD +
                    (size_t)qt * QB * D_HEAD;

  if (tid < QB) rinv_s[tid] = out_base[tid];  // written by k_rowsum

  // Q A-frags, hi/lo split, pre-scaled by 1/8
  const int arow = qt * QB + rg * 32 + (lane & 31);
  const float* qp = Q + (size_t)arow * D_HEAD + ((lane >> 5) * 8);
  short8 ahi[4], alo[4];
#pragma unroll
  for (int ks = 0; ks < 4; ++ks) {
    floatx4 x0 = *(const floatx4*)(qp + ks * 16);
    floatx4 x1 = *(const floatx4*)(qp + ks * 16 + 4);
    ushort8v uh, ul;
#pragma unroll
    for (int j = 0; j < 4; ++j) {
      float xa = x0[j] * 0.125f;
      unsigned short ha = f2bf(xa);
      uh[j] = ha; ul[j] = f2bf(xa - bf2f(ha));
      float xb = x1[j] * 0.125f;
      unsigned short hb = f2bf(xb);
      uh[4 + j] = hb; ul[4 + j] = f2bf(xb - bf2f(hb));
    }
    ahi[ks] = __builtin_bit_cast(short8, uh);
    alo[ks] = __builtin_bit_cast(short8, ul);
  }
  __syncthreads();

  // preload 1/rowsum for this lane's C/D rows
  floatx4 rvec[4];
  {
    const int rb = rg * 32 + 4 * (lane >> 5);
#pragma unroll
    for (int m = 0; m < 4; ++m) rvec[m] = *(const floatx4*)&rinv_s[rb + 8 * m];
  }

  f32x16 oacc = {};
  const int srow = tid >> 2;
  const int scol = (tid & 3) * 16;
  const int bcol = cg * 32 + (lane & 31);
  const int boff = (lane >> 5) * 8;

  for (int ch = 0; ch < NCHUNK; ++ch) {
    const int kk0 = ch * KB;
    {  // stage K hi/lo
      const float* src = K + (size_t)(kk0 + srow) * D_HEAD + scol;
      floatx4 v0 = *(const floatx4*)(src);
      floatx4 v1 = *(const floatx4*)(src + 4);
      floatx4 v2 = *(const floatx4*)(src + 8);
      floatx4 v3 = *(const floatx4*)(src + 12);
      ushort8v h0, h1, l0, l1;
#pragma unroll
      for (int j = 0; j < 4; ++j) {
        unsigned short a0 = f2bf(v0[j]); h0[j] = a0; l0[j] = f2bf(v0[j] - bf2f(a0));
        unsigned short a1 = f2bf(v1[j]); h0[4+j] = a1; l0[4+j] = f2bf(v1[j] - bf2f(a1));
        unsigned short a2 = f2bf(v2[j]); h1[j] = a2; l1[j] = f2bf(v2[j] - bf2f(a2));
        unsigned short a3 = f2bf(v3[j]); h1[4+j] = a3; l1[4+j] = f2bf(v3[j] - bf2f(a3));
      }
      *(ushort8v*)&KhiS[srow * KPAD + scol] = h0;
      *(ushort8v*)&KhiS[srow * KPAD + scol + 8] = h1;
      *(ushort8v*)&KloS[srow * KPAD + scol] = l0;
      *(ushort8v*)&KloS[srow * KPAD + scol + 8] = l1;
    }
    {  // stage V transposed (fp16): wave w reads rows kk0+half*64+w*8+i (coalesced),
       // writes Vt[d][kk]; write stride 272B = 17*16B (odd) -> conflict-free
#pragma unroll
      for (int half = 0; half < 2; ++half) {
        const float* vsrc = V + (size_t)(kk0 + half * 64 + wid * 8) * D_HEAD + lane;
        ushort8v hv;
#pragma unroll
        for (int i = 0; i < 8; ++i) hv[i] = f2h(vsrc[(size_t)i * D_HEAD]);
        *(ushort8v*)&VtS[lane * PPAD + half * 64 + wid * 8] = hv;
      }
    }
    __syncthreads();

    // QK^T with hi/lo split (3 MFMAs per k-step): err ~1e-5 vs fp32
    f32x16 acc = {};
#pragma unroll
    for (int ks = 0; ks < 4; ++ks) {
      ushort8v bhu = *(const ushort8v*)&KhiS[bcol * KPAD + ks * 16 + boff];
      ushort8v blu = *(const ushort8v*)&KloS[bcol * KPAD + ks * 16 + boff];
      short8 bh8 = __builtin_bit_cast(short8, bhu);
      short8 bl8 = __builtin_bit_cast(short8, blu);
      acc = __builtin_amdgcn_mfma_f32_32x32x16_bf16(alo[ks], bh8, acc, 0, 0, 0);
      acc = __builtin_amdgcn_mfma_f32_32x32x16_bf16(ahi[ks], bl8, acc, 0, 0, 0);
      acc = __builtin_amdgcn_mfma_f32_32x32x16_bf16(ahi[ks], bh8, acc, 0, 0, 0);
    }

    // exp -> normalize -> attn store (nontemporal stream) + fp16 stash
    {
      const int rbase = rg * 32 + 4 * (lane >> 5);
      const int colg = kk0 + cg * 32 + (lane & 31);
#pragma unroll
      for (int i = 0; i < 16; ++i) {
        float p = EXP2F(acc[i] * LOG2E);
        float at = p * rvec[i >> 2][i & 3];
        const int rl = rbase + (i & 3) + 8 * (i >> 2);
        __builtin_nontemporal_store(at, &attn_base[(size_t)rl * S_LEN + colg]);
        Pst[rl * PPAD + cg * 32 + (lane & 31)] = f2h(at);
      }
    }
    __syncthreads();

    // PV: out += P(fp16) @ V(fp16); waves split the 128-kk range in halves
#pragma unroll
    for (int ks = 0; ks < 4; ++ks) {
      const int kofs = kh * 64 + ks * 16 + boff;
      ushort8v pu = *(const ushort8v*)&Pst[(rg * 32 + (lane & 31)) * PPAD + kofs];
      ushort8v vu = *(const ushort8v*)&VtS[(dg * 32 + (lane & 31)) * PPAD + kofs];
      oacc = __builtin_amdgcn_mfma_f32_32x32x16_f16(
          __builtin_bit_cast(half8, pu), __builtin_bit_cast(half8, vu), oacc, 0, 0, 0);
    }
    __syncthreads();
  }

  // reduce the two kk-halves through LDS (alias KhiS: 16 KiB needed, 18 KiB there)
  float* red = (float*)KhiS;
  const int t4 = wid & 3;
  if (kh == 1) {
#pragma unroll
    for (int i = 0; i < 16; ++i) red[t4 * 1024 + i * 64 + lane] = oacc[i];
  }
  __syncthreads();
  if (kh == 0) {
#pragma unroll
    for (int i = 0; i < 16; ++i) oacc[i] += red[t4 * 1024 + i * 64 + lane];
    const int rbase = rg * 32 + 4 * (lane >> 5);
#pragma unroll
    for (int i = 0; i < 16; ++i) {
      const int rl = rbase + (i & 3) + 8 * (i >> 2);
      out_base[(size_t)rl * D_HEAD + dg * 32 + (lane & 31)] = oacc[i];
    }
  }
}

extern "C" void kernel_launch(void* const* d_in, const int* in_sizes, int n_in,
                              void* d_out, int out_size, void* d_ws, size_t ws_size,
                              hipStream_t stream) {
  const float* q = (const float*)d_in[0];
  const float* k = (const float*)d_in[1];
  const float* v = (const float*)d_in[2];
  float* out = (float*)d_out;
  (void)d_ws; (void)ws_size; (void)in_sizes; (void)n_in; (void)out_size;

  dim3 grid(32 * (S_LEN / QB));  // 1024 blocks: bh = bx>>5, qt = bx&31
  dim3 blk(512);
  hipLaunchKernelGGL(k_rowsum, grid, blk, 0, stream, q, k, out);
  hipLaunchKernelGGL(k_attn, grid, blk, 0, stream, q, k, v, out);
}